// Round 1
// baseline (1008.227 us; speedup 1.0000x reference)
//
#include <hip/hip_runtime.h>

// SparseConvolutionDownsample: rulebook sparse conv (gather -> GEMM -> scatter-add)
// + BatchNorm over active sites + LeakyReLU(0.333).
//
// Fixed problem constants (from reference): C_IN=64, C_OUT=128, K=4,
// P = in_sizes[4]/K = 262144, n_out = out_size/C_OUT = 262144.

#define C_IN   64
#define C_OUT  128
#define KOFF   4
#define TILE_P 128
#define SF_LD  66            // sF row stride: 66 floats -> 8-row strided reads are 2-way (free)
#define BN_EPS 1e-4f
#define LEAK   0.333f

// ---------------------------------------------------------------------------
// Kernel 1: per-offset gather + 128x128 GEMM tile + atomic scatter-add.
// Block = 256 threads. tx = tid&15 -> cols {tx + 16j, j=0..7} (coalesced),
// ty = tid>>4 -> rows {8ty .. 8ty+7}. Each thread: 8x8 fp32 accumulators.
// ---------------------------------------------------------------------------
__global__ __launch_bounds__(256) void scatter_gemm_kernel(
    const float* __restrict__ feats, const float* __restrict__ W,
    const int* __restrict__ in_idx, const int* __restrict__ out_idx,
    float* __restrict__ out, int P)
{
    __shared__ float sW[C_IN][C_OUT];       // 32 KB
    __shared__ float sF[TILE_P][SF_LD];     // 33 KB (stride 66: float2-aligned, 2-way banks)

    const int tid = threadIdx.x;
    const int k  = blockIdx.y;
    const int p0 = blockIdx.x * TILE_P;

    // Stage W[k] (64x128 = 2048 float4) -> LDS, coalesced.
    const float4* Wk4 = (const float4*)(W + (size_t)k * C_IN * C_OUT);
    float4* sW4 = (float4*)&sW[0][0];
    #pragma unroll
    for (int i = tid; i < C_IN * C_OUT / 4; i += 256)
        sW4[i] = Wk4[i];

    // Stage gathered feats rows: 128 rows x 16 float4. 16 consecutive threads
    // load one row (coalesced 256B). Store as 2x float2 (stride 66 not /4).
    for (int i = tid; i < TILE_P * (C_IN / 4); i += 256) {
        int r  = i >> 4;
        int c4 = i & 15;
        int src = in_idx[(size_t)k * P + p0 + r];
        float4 v = ((const float4*)(feats + (size_t)src * C_IN))[c4];
        float* dst = &sF[r][c4 * 4];
        ((float2*)dst)[0] = make_float2(v.x, v.y);
        ((float2*)dst)[1] = make_float2(v.z, v.w);
    }
    __syncthreads();

    const int tx = tid & 15;   // col base: tx + 16*j
    const int ty = tid >> 4;   // row base: 8*ty + r

    float acc[8][8];
    #pragma unroll
    for (int r = 0; r < 8; ++r)
        #pragma unroll
        for (int j = 0; j < 8; ++j) acc[r][j] = 0.f;

    for (int kk = 0; kk < C_IN; ++kk) {
        float w[8], f[8];
        #pragma unroll
        for (int j = 0; j < 8; ++j) w[j] = sW[kk][tx + 16 * j];   // 16 consecutive banks, 4x broadcast
        #pragma unroll
        for (int r = 0; r < 8; ++r) f[r] = sF[8 * ty + r][kk];    // 4 addrs/wave, 2-way banks
        #pragma unroll
        for (int r = 0; r < 8; ++r)
            #pragma unroll
            for (int j = 0; j < 8; ++j)
                acc[r][j] = fmaf(f[r], w[j], acc[r][j]);
    }

    // Scatter-add: per row, 16 lanes cover 128 cols in 16-strided groups -> coalesced atomics.
    #pragma unroll
    for (int r = 0; r < 8; ++r) {
        int orow = out_idx[(size_t)k * P + p0 + 8 * ty + r];
        float* op = out + (size_t)orow * C_OUT + tx;
        #pragma unroll
        for (int j = 0; j < 8; ++j)
            atomicAdd(op + 16 * j, acc[r][j]);
    }
}

// ---------------------------------------------------------------------------
// Kernel 2: per-channel sum / sumsq over out [n_out x 128]. float4 loads.
// ---------------------------------------------------------------------------
__global__ __launch_bounds__(256) void bn_stats_kernel(
    const float* __restrict__ out, float* __restrict__ stats, int n_out)
{
    const int tid = threadIdx.x;
    const int c4   = tid & 31;   // float4 index within a row (32*4 = 128 ch)
    const int rgrp = tid >> 5;   // 8 rows per block-iteration

    float4 s  = make_float4(0.f, 0.f, 0.f, 0.f);
    float4 s2 = make_float4(0.f, 0.f, 0.f, 0.f);
    for (int r = blockIdx.x * 8 + rgrp; r < n_out; r += gridDim.x * 8) {
        float4 v = ((const float4*)(out + (size_t)r * C_OUT))[c4];
        s.x += v.x; s.y += v.y; s.z += v.z; s.w += v.w;
        s2.x += v.x * v.x; s2.y += v.y * v.y; s2.z += v.z * v.z; s2.w += v.w * v.w;
    }

    __shared__ float4 red[256], red2[256];
    red[tid] = s; red2[tid] = s2;
    __syncthreads();
    if (tid < 32) {
        #pragma unroll
        for (int j = 1; j < 8; ++j) {
            float4 a = red[tid + 32 * j], b = red2[tid + 32 * j];
            s.x += a.x; s.y += a.y; s.z += a.z; s.w += a.w;
            s2.x += b.x; s2.y += b.y; s2.z += b.z; s2.w += b.w;
        }
        atomicAdd(&stats[4 * tid + 0], s.x);
        atomicAdd(&stats[4 * tid + 1], s.y);
        atomicAdd(&stats[4 * tid + 2], s.z);
        atomicAdd(&stats[4 * tid + 3], s.w);
        atomicAdd(&stats[C_OUT + 4 * tid + 0], s2.x);
        atomicAdd(&stats[C_OUT + 4 * tid + 1], s2.y);
        atomicAdd(&stats[C_OUT + 4 * tid + 2], s2.z);
        atomicAdd(&stats[C_OUT + 4 * tid + 3], s2.w);
    }
}

// ---------------------------------------------------------------------------
// Kernel 3: normalize + LeakyReLU, in place. float4 grid-stride.
// ---------------------------------------------------------------------------
__global__ __launch_bounds__(256) void bn_apply_kernel(
    float* __restrict__ out, const float* __restrict__ stats,
    const float* __restrict__ gamma, const float* __restrict__ beta,
    int n_out, float inv_n)
{
    const size_t total = (size_t)n_out * (C_OUT / 4);
    size_t i = (size_t)blockIdx.x * 256 + threadIdx.x;
    const int c = (int)(i & 31) * 4;   // channel base; invariant (stride % 32 == 0)

    float4 sc, sh;
    {
        float m0 = stats[c + 0] * inv_n, m1 = stats[c + 1] * inv_n,
              m2 = stats[c + 2] * inv_n, m3 = stats[c + 3] * inv_n;
        float v0 = stats[C_OUT + c + 0] * inv_n - m0 * m0;
        float v1 = stats[C_OUT + c + 1] * inv_n - m1 * m1;
        float v2 = stats[C_OUT + c + 2] * inv_n - m2 * m2;
        float v3 = stats[C_OUT + c + 3] * inv_n - m3 * m3;
        sc.x = gamma[c + 0] * rsqrtf(v0 + BN_EPS);
        sc.y = gamma[c + 1] * rsqrtf(v1 + BN_EPS);
        sc.z = gamma[c + 2] * rsqrtf(v2 + BN_EPS);
        sc.w = gamma[c + 3] * rsqrtf(v3 + BN_EPS);
        sh.x = beta[c + 0] - m0 * sc.x;
        sh.y = beta[c + 1] - m1 * sc.y;
        sh.z = beta[c + 2] - m2 * sc.z;
        sh.w = beta[c + 3] - m3 * sc.w;
    }

    float4* o4 = (float4*)out;
    for (; i < total; i += (size_t)gridDim.x * 256) {
        float4 v = o4[i];
        v.x = v.x * sc.x + sh.x; v.x = v.x >= 0.f ? v.x : LEAK * v.x;
        v.y = v.y * sc.y + sh.y; v.y = v.y >= 0.f ? v.y : LEAK * v.y;
        v.z = v.z * sc.z + sh.z; v.z = v.z >= 0.f ? v.z : LEAK * v.z;
        v.w = v.w * sc.w + sh.w; v.w = v.w >= 0.f ? v.w : LEAK * v.w;
        o4[i] = v;
    }
}

// ---------------------------------------------------------------------------
extern "C" void kernel_launch(void* const* d_in, const int* in_sizes, int n_in,
                              void* d_out, int out_size, void* d_ws, size_t ws_size,
                              hipStream_t stream)
{
    const float* feats  = (const float*)d_in[0];
    const float* W      = (const float*)d_in[1];
    const float* gamma  = (const float*)d_in[2];
    const float* beta   = (const float*)d_in[3];
    const int*  in_idx  = (const int*)d_in[4];
    const int*  out_idx = (const int*)d_in[5];

    const int P     = in_sizes[4] / KOFF;     // 262144
    const int n_out = out_size / C_OUT;       // 262144
    float* out   = (float*)d_out;
    float* stats = (float*)d_ws;              // 256 floats: sum[128], sumsq[128]

    hipMemsetAsync(d_out, 0, (size_t)out_size * sizeof(float), stream);
    hipMemsetAsync(d_ws, 0, 2 * C_OUT * sizeof(float), stream);

    dim3 grid_g(P / TILE_P, KOFF);            // 2048 x 4
    scatter_gemm_kernel<<<grid_g, 256, 0, stream>>>(feats, W, in_idx, out_idx, out, P);
    bn_stats_kernel<<<1024, 256, 0, stream>>>(out, stats, n_out);
    bn_apply_kernel<<<2048, 256, 0, stream>>>(out, stats, gamma, beta, n_out, 1.0f / n_out);
}